// Round 15
// baseline (414.082 us; speedup 1.0000x reference)
//
#include <hip/hip_runtime.h>
#include <hip/hip_bf16.h>

#define DIM 768
#define TD 2304
#define NB 8
#define NS 4096
#define NE 6

typedef __attribute__((ext_vector_type(8))) short bf16x8;
typedef __attribute__((ext_vector_type(4))) float f32x4;

// ws layout (float offsets)
#define OFF_BPK    0        // [72 ks][2 m][64 lane][8 j] u16 = 73728 u16 = 36864 f
#define OFF_A2F    36864    // [2304][6] f32 delta-mean fold
#define OFF_CB0    50688    // [16]
#define OFF_ACCSUM 50704    // [8][6] + pad = 64
#define OFF_CONSTB 50768    // [8][6] + pad = 64
#define OFF_QP2    50832    // [2 khalf][32768][12] = 786432

__device__ __forceinline__ unsigned short f2bf(float f) {
    union { float f; unsigned u; } a; a.f = f;
    unsigned r = a.u + 0x7FFFu + ((a.u >> 16) & 1u);
    return (unsigned short)(r >> 16);
}

__device__ __forceinline__ bf16x8 pack8(float4 a, float4 b) {
    union { bf16x8 v; __hip_bfloat162 h[4]; } u;
    u.h[0] = __float22bfloat162_rn(make_float2(a.x, a.y));
    u.h[1] = __float22bfloat162_rn(make_float2(a.z, a.w));
    u.h[2] = __float22bfloat162_rn(make_float2(b.x, b.y));
    u.h[3] = __float22bfloat162_rn(make_float2(b.z, b.w));
    return u.v;
}

// ---------------- kernel B: fold coefficients into MFMA B-fragment layout ----
__global__ __launch_bounds__(256) void k_fold(
    const float* __restrict__ Wspat, const float* __restrict__ Wtemp,
    const float* __restrict__ Wsync, const float* __restrict__ Wroute,
    const float* __restrict__ Wglob, const float* __restrict__ bglob,
    const float* __restrict__ broute, const float* __restrict__ bspat,
    const float* __restrict__ btemp, const float* __restrict__ bsync,
    unsigned short* __restrict__ Bpk, float* __restrict__ A2F,
    float* __restrict__ cb0, float* __restrict__ accsum)
{
    __shared__ float lwr[288 * NE];
    __shared__ float lgf[224 * NE];
    const int t = threadIdx.x;
    for (int i = t; i < 288 * NE; i += 256) lwr[i] = Wroute[i];
    __syncthreads();
    if (t < 224) {
        float g[NE] = {0, 0, 0, 0, 0, 0};
        for (int o = 0; o < 64; ++o) {
            const float w = Wglob[t * 64 + o];
            #pragma unroll
            for (int e = 0; e < NE; ++e) g[e] += w * lwr[(224 + o) * NE + e];
        }
        #pragma unroll
        for (int e = 0; e < NE; ++e) lgf[t * NE + e] = g[e];
    }
    __syncthreads();
    if (blockIdx.x == 0) {
        if (t < NE) {
            float a = broute[t];
            for (int o = 0; o < 64; ++o)  a += bglob[o] * lwr[(224 + o) * NE + t];
            for (int o = 0; o < 128; ++o) a += bspat[o] * (lwr[o * NE + t] + lgf[o * NE + t]);
            for (int o = 0; o < 64; ++o)  a += btemp[o] * (lwr[(128 + o) * NE + t] + lgf[(128 + o) * NE + t]);
            for (int o = 0; o < 32; ++o)  a += bsync[o] * (lwr[(192 + o) * NE + t] + lgf[(192 + o) * NE + t]);
            cb0[t] = a;
        }
        if (t >= 128 && t < 192) accsum[t - 128] = 0.f;
    }

    const int d = blockIdx.x * 256 + t;          // exactly 2304 threads
    const int st = d / DIM, dd = d - st * DIM;

    float p[NE] = {0, 0, 0, 0, 0, 0}, a2[NE] = {0, 0, 0, 0, 0, 0};
    for (int o = 0; o < 64; ++o) {
        const float w = Wtemp[d * 64 + o];
        #pragma unroll
        for (int e = 0; e < NE; ++e) {
            p[e]  += w * lwr[(128 + o) * NE + e];
            a2[e] += w * lgf[(128 + o) * NE + e];
        }
    }
    float qq[NE], a1[NE];
    #pragma unroll
    for (int e = 0; e < NE; ++e) { qq[e] = p[e]; a1[e] = 0.f; }
    for (int o = 0; o < 128; ++o) {
        const float w = Wspat[d * 128 + o];
        #pragma unroll
        for (int e = 0; e < NE; ++e) {
            qq[e] += w * lwr[o * NE + e];
            a1[e] += w * lgf[o * NE + e];
        }
    }
    if (st != 0) {
        const float sg = (st == 1) ? 1.f : -1.f;
        for (int o = 0; o < 32; ++o) {
            const float w = sg * Wsync[dd * 32 + o];
            #pragma unroll
            for (int e = 0; e < NE; ++e) {
                qq[e] += w * lwr[(192 + o) * NE + e];
                a1[e] += w * lgf[(192 + o) * NE + e];
            }
        }
    }
    // B-fragment scatter: B[k][n], k=d. frag: lane = (kk>>3)*16 + n, j = kk&7.
    const int ks = d >> 5, kk = d & 31;
    const int lh = (kk >> 3) * 16, j = kk & 7;
    unsigned short* b0 = Bpk + ks * 1024 + j;          // m=0 (Q/P outs 0-11)
    unsigned short* b1 = b0 + 512;                     // m=1 (A1 outs 0-5)
    #pragma unroll
    for (int e = 0; e < NE; ++e) {
        b0[(lh + e) * 8]     = f2bf(qq[e]);
        b0[(lh + 6 + e) * 8] = f2bf(p[e]);
        b1[(lh + e) * 8]     = f2bf(a1[e]);
        A2F[d * NE + e] = a2[e];
    }
}

// ---------------- kernel C: MFMA streaming GEMM, no LDS, no barriers ----------------
// r12 structure verbatim; ONLY change: __launch_bounds__(256, 8) -> VGPR cap 64,
// 8 blocks/CU, 32 waves/CU. 8 waves/SIMD interleave their load-stall windows,
// which is how streaming kernels (m13) fill the memory system. All 1024 blocks
// co-resident. B-loads identical across the 4 waves of a block -> L1-served.

#define GLOADX(A0, A1, A2, A3, C) { \
    const int gc_ = khalf * 1152 + (C) * 64; \
    const int st_ = gc_ / DIM; \
    const float* Xp_ = (st_ == 0) ? xt : ((st_ == 1) ? xa : xv); \
    const float* Xr_ = Xp_ + rowoff + (gc_ - st_ * DIM); \
    A0 = *(const float4*)(Xr_);      A1 = *(const float4*)(Xr_ + 4); \
    A2 = *(const float4*)(Xr_ + 32); A3 = *(const float4*)(Xr_ + 36); }

#define BLOAD(C, B00, B01, B10, B11) { \
    const unsigned short* bp = Bpk + ((khalf * 18 + (C)) << 11) + (l << 3); \
    B00 = *(const bf16x8*)(bp); \
    B01 = *(const bf16x8*)(bp + 512); \
    B10 = *(const bf16x8*)(bp + 1024); \
    B11 = *(const bf16x8*)(bp + 1536); }

#define CMPT(A0, A1, A2, A3, B00, B01, B10, B11) { \
    const bf16x8 fA0 = pack8(A0, A1); \
    const bf16x8 fA1 = pack8(A2, A3); \
    acc0 = __builtin_amdgcn_mfma_f32_16x16x32_bf16(fA0, B00, acc0, 0, 0, 0); \
    acc1 = __builtin_amdgcn_mfma_f32_16x16x32_bf16(fA0, B01, acc1, 0, 0, 0); \
    acc0 = __builtin_amdgcn_mfma_f32_16x16x32_bf16(fA1, B10, acc0, 0, 0, 0); \
    acc1 = __builtin_amdgcn_mfma_f32_16x16x32_bf16(fA1, B11, acc1, 0, 0, 0); }

__global__ __launch_bounds__(256, 8) void k_main(
    const float* __restrict__ xt, const float* __restrict__ xa, const float* __restrict__ xv,
    const unsigned short* __restrict__ Bpk, float* __restrict__ accsum,
    float* __restrict__ qp2)
{
    const int t = threadIdx.x;
    const int l = t & 63;
    const int w = t >> 6;
    const int bid = blockIdx.x;
    const int khalf = bid & 1;
    const int rblk = bid >> 1;
    const int rb0 = rblk << 6;
    const int bb = rblk >> 6;

    const int arow = rb0 + w * 16 + (l & 15);
    const size_t rowoff = (size_t)arow * DIM + (l >> 4) * 8;

    f32x4 acc0 = {0.f, 0.f, 0.f, 0.f};
    f32x4 acc1 = {0.f, 0.f, 0.f, 0.f};

    float4 pa0, pa1, pa2, pa3, pb0, pb1, pb2, pb3;
    bf16x8 Ba00, Ba01, Ba10, Ba11, Bb00, Bb01, Bb10, Bb11;

    GLOADX(pa0, pa1, pa2, pa3, 0)
    BLOAD(0, Ba00, Ba01, Ba10, Ba11)
    GLOADX(pb0, pb1, pb2, pb3, 1)
    BLOAD(1, Bb00, Bb01, Bb10, Bb11)

    #pragma unroll 1
    for (int c = 0; c < 16; c += 2) {
        CMPT(pa0, pa1, pa2, pa3, Ba00, Ba01, Ba10, Ba11)
        GLOADX(pa0, pa1, pa2, pa3, c + 2)
        BLOAD(c + 2, Ba00, Ba01, Ba10, Ba11)
        CMPT(pb0, pb1, pb2, pb3, Bb00, Bb01, Bb10, Bb11)
        GLOADX(pb0, pb1, pb2, pb3, c + 3)
        BLOAD(c + 3, Bb00, Bb01, Bb10, Bb11)
    }
    CMPT(pa0, pa1, pa2, pa3, Ba00, Ba01, Ba10, Ba11)
    CMPT(pb0, pb1, pb2, pb3, Bb00, Bb01, Bb10, Bb11)

    // epilogue: D layout col=lane&15, row=(lane>>4)*4+reg
    const int c_out = l & 15, rgrp = l >> 4;
    float* qph = qp2 + (size_t)khalf * ((size_t)NB * NS * 12);
    if (c_out < 12) {
        const size_t rbase = (size_t)(rb0 + w * 16 + rgrp * 4) * 12 + c_out;
        qph[rbase]      = acc0[0];
        qph[rbase + 12] = acc0[1];
        qph[rbase + 24] = acc0[2];
        qph[rbase + 36] = acc0[3];
    }
    float v = acc1[0] + acc1[1] + acc1[2] + acc1[3];
    v += __shfl_xor(v, 16, 64);
    v += __shfl_xor(v, 32, 64);
    if (rgrp == 0 && c_out < 6)
        atomicAdd(&accsum[bb * NE + c_out], v);
}

// ---------------- kernel D: per-batch global constant ----------------
__global__ __launch_bounds__(256) void k_const(
    const float* __restrict__ xt, const float* __restrict__ xa, const float* __restrict__ xv,
    const float* __restrict__ accsum, const float* __restrict__ A2F,
    const float* __restrict__ cb0, float* __restrict__ constb)
{
    const int b = blockIdx.x, t = threadIdx.x;
    float acc[NE] = {0, 0, 0, 0, 0, 0};
    for (int f = t; f < TD; f += 256) {
        const int st = f / DIM, dd = f - st * DIM;
        const float* Xp = ((st == 0) ? xt : ((st == 1) ? xa : xv)) + (size_t)b * NS * DIM;
        const float dm = Xp[(size_t)(NS - 1) * DIM + dd] - Xp[dd];
        const float* Ap = A2F + f * NE;
        #pragma unroll
        for (int e = 0; e < NE; ++e) acc[e] += dm * Ap[e];
    }
    #pragma unroll
    for (int e = 0; e < NE; ++e)
        for (int m = 1; m < 64; m <<= 1) acc[e] += __shfl_xor(acc[e], m, 64);
    __shared__ float wred[4][NE];
    if ((t & 63) == 0) {
        #pragma unroll
        for (int e = 0; e < NE; ++e) wred[t >> 6][e] = acc[e];
    }
    __syncthreads();
    if (t < NE) {
        const float inv = 1.f / 4096.f;
        const float dsum = wred[0][t] + wred[1][t] + wred[2][t] + wred[3][t];
        constb[b * NE + t] = cb0[t] + accsum[b * NE + t] * inv + dsum * inv;
    }
}

// ---------------- kernel E: combine q - shifted p + const ----------------
__global__ __launch_bounds__(256) void k_add(
    const float* __restrict__ qp2, const float* __restrict__ constb, float* __restrict__ out)
{
    const int row = blockIdx.x * 256 + threadIdx.x;   // 32768 rows exact
    const int b = row >> 12, s = row & (NS - 1);
    const int rowp = (s == 0) ? row : row - 1;
    const size_t H = (size_t)NB * NS * 12;
    const float* q0 = qp2 + (size_t)row * 12;
    const float* q1 = qp2 + H + (size_t)row * 12;
    const float* p0 = qp2 + (size_t)rowp * 12 + 6;
    const float* p1 = qp2 + H + (size_t)rowp * 12 + 6;
    float* op = out + (size_t)row * NE;
    #pragma unroll
    for (int e = 0; e < NE; ++e)
        op[e] = constb[b * NE + e] + q0[e] + q1[e] - p0[e] - p1[e];
}

extern "C" void kernel_launch(void* const* d_in, const int* in_sizes, int n_in,
                              void* d_out, int out_size, void* d_ws, size_t ws_size,
                              hipStream_t stream)
{
    const float* xt     = (const float*)d_in[0];
    const float* xa     = (const float*)d_in[1];
    const float* xv     = (const float*)d_in[2];
    const float* Wspat  = (const float*)d_in[3];
    const float* bspat  = (const float*)d_in[4];
    const float* Wtemp  = (const float*)d_in[5];
    const float* btemp  = (const float*)d_in[6];
    const float* Wsync  = (const float*)d_in[7];
    const float* bsync  = (const float*)d_in[8];
    const float* Wglob  = (const float*)d_in[9];
    const float* bglob  = (const float*)d_in[10];
    const float* Wroute = (const float*)d_in[11];
    const float* broute = (const float*)d_in[12];
    float* out = (float*)d_out;

    float* ws = (float*)d_ws;
    unsigned short* Bpk = (unsigned short*)(ws + OFF_BPK);
    float* A2F    = ws + OFF_A2F;
    float* cb0    = ws + OFF_CB0;
    float* accsum = ws + OFF_ACCSUM;
    float* constb = ws + OFF_CONSTB;
    float* qp2    = ws + OFF_QP2;

    hipMemsetAsync(Bpk, 0, 73728 * sizeof(unsigned short), stream);
    k_fold<<<9, 256, 0, stream>>>(Wspat, Wtemp, Wsync, Wroute, Wglob, bglob,
                                  broute, bspat, btemp, bsync, Bpk, A2F, cb0, accsum);
    k_main<<<1024, 256, 0, stream>>>(xt, xa, xv, Bpk, accsum, qp2);
    k_const<<<8, 256, 0, stream>>>(xt, xa, xv, accsum, A2F, cb0, constb);
    k_add<<<128, 256, 0, stream>>>(qp2, constb, out);
}

// Round 16
// 115.572 us; speedup vs baseline: 3.5829x; 3.5829x over previous
//
#include <hip/hip_runtime.h>
#include <hip/hip_bf16.h>

#define DIM 768
#define TD 2304
#define NB 8
#define NS 4096
#define NE 6

typedef __attribute__((ext_vector_type(8))) short bf16x8;
typedef __attribute__((ext_vector_type(4))) float f32x4;

// ws layout (float offsets)
#define OFF_BPK    0        // [72 ks][2 m][64 lane][8 j] u16 = 73728 u16 = 36864 f
#define OFF_A2F    36864    // [2304][6] f32 delta-mean fold
#define OFF_CB0    50688    // [16]
#define OFF_ACCSUM 50704    // [8][6] + pad = 64
#define OFF_CONSTB 50768    // [8][6] + pad = 64
#define OFF_QP2    50832    // [2 khalf][32768][12] = 786432

__device__ __forceinline__ unsigned short f2bf(float f) {
    union { float f; unsigned u; } a; a.f = f;
    unsigned r = a.u + 0x7FFFu + ((a.u >> 16) & 1u);
    return (unsigned short)(r >> 16);
}

__device__ __forceinline__ bf16x8 pack8(float4 a, float4 b) {
    union { bf16x8 v; __hip_bfloat162 h[4]; } u;
    u.h[0] = __float22bfloat162_rn(make_float2(a.x, a.y));
    u.h[1] = __float22bfloat162_rn(make_float2(a.z, a.w));
    u.h[2] = __float22bfloat162_rn(make_float2(b.x, b.y));
    u.h[3] = __float22bfloat162_rn(make_float2(b.z, b.w));
    return u.v;
}

// ---------------- kernel B: fold coefficients into MFMA B-fragment layout ----
__global__ __launch_bounds__(256) void k_fold(
    const float* __restrict__ Wspat, const float* __restrict__ Wtemp,
    const float* __restrict__ Wsync, const float* __restrict__ Wroute,
    const float* __restrict__ Wglob, const float* __restrict__ bglob,
    const float* __restrict__ broute, const float* __restrict__ bspat,
    const float* __restrict__ btemp, const float* __restrict__ bsync,
    unsigned short* __restrict__ Bpk, float* __restrict__ A2F,
    float* __restrict__ cb0, float* __restrict__ accsum)
{
    __shared__ float lwr[288 * NE];
    __shared__ float lgf[224 * NE];
    const int t = threadIdx.x;
    for (int i = t; i < 288 * NE; i += 256) lwr[i] = Wroute[i];
    __syncthreads();
    if (t < 224) {
        float g[NE] = {0, 0, 0, 0, 0, 0};
        for (int o = 0; o < 64; ++o) {
            const float w = Wglob[t * 64 + o];
            #pragma unroll
            for (int e = 0; e < NE; ++e) g[e] += w * lwr[(224 + o) * NE + e];
        }
        #pragma unroll
        for (int e = 0; e < NE; ++e) lgf[t * NE + e] = g[e];
    }
    __syncthreads();
    if (blockIdx.x == 0) {
        if (t < NE) {
            float a = broute[t];
            for (int o = 0; o < 64; ++o)  a += bglob[o] * lwr[(224 + o) * NE + t];
            for (int o = 0; o < 128; ++o) a += bspat[o] * (lwr[o * NE + t] + lgf[o * NE + t]);
            for (int o = 0; o < 64; ++o)  a += btemp[o] * (lwr[(128 + o) * NE + t] + lgf[(128 + o) * NE + t]);
            for (int o = 0; o < 32; ++o)  a += bsync[o] * (lwr[(192 + o) * NE + t] + lgf[(192 + o) * NE + t]);
            cb0[t] = a;
        }
        if (t >= 128 && t < 192) accsum[t - 128] = 0.f;
    }

    const int d = blockIdx.x * 256 + t;          // exactly 2304 threads
    const int st = d / DIM, dd = d - st * DIM;

    float p[NE] = {0, 0, 0, 0, 0, 0}, a2[NE] = {0, 0, 0, 0, 0, 0};
    for (int o = 0; o < 64; ++o) {
        const float w = Wtemp[d * 64 + o];
        #pragma unroll
        for (int e = 0; e < NE; ++e) {
            p[e]  += w * lwr[(128 + o) * NE + e];
            a2[e] += w * lgf[(128 + o) * NE + e];
        }
    }
    float qq[NE], a1[NE];
    #pragma unroll
    for (int e = 0; e < NE; ++e) { qq[e] = p[e]; a1[e] = 0.f; }
    for (int o = 0; o < 128; ++o) {
        const float w = Wspat[d * 128 + o];
        #pragma unroll
        for (int e = 0; e < NE; ++e) {
            qq[e] += w * lwr[o * NE + e];
            a1[e] += w * lgf[o * NE + e];
        }
    }
    if (st != 0) {
        const float sg = (st == 1) ? 1.f : -1.f;
        for (int o = 0; o < 32; ++o) {
            const float w = sg * Wsync[dd * 32 + o];
            #pragma unroll
            for (int e = 0; e < NE; ++e) {
                qq[e] += w * lwr[(192 + o) * NE + e];
                a1[e] += w * lgf[(192 + o) * NE + e];
            }
        }
    }
    // B-fragment scatter: B[k][n], k=d. frag: lane = (kk>>3)*16 + n, j = kk&7.
    const int ks = d >> 5, kk = d & 31;
    const int lh = (kk >> 3) * 16, j = kk & 7;
    unsigned short* b0 = Bpk + ks * 1024 + j;          // m=0 (Q/P outs 0-11)
    unsigned short* b1 = b0 + 512;                     // m=1 (A1 outs 0-5)
    #pragma unroll
    for (int e = 0; e < NE; ++e) {
        b0[(lh + e) * 8]     = f2bf(qq[e]);
        b0[(lh + 6 + e) * 8] = f2bf(p[e]);
        b1[(lh + e) * 8]     = f2bf(a1[e]);
        A2F[d * NE + e] = a2[e];
    }
}

// ---------------- kernel C: MFMA streaming GEMM, no LDS, no barriers ----------------
// r12 structure, SINGLE-buffered body (no per-wave ping-pong: depth 0/1/2 all
// measured equal — TLP is the latency hider). __launch_bounds__(256, 6):
// VGPR budget ~85 >> est. 52 live, 6 blocks/CU = 24 waves/CU resident.

#define GLOADX(A0, A1, A2, A3, C) { \
    const int gc_ = khalf * 1152 + (C) * 64; \
    const int st_ = gc_ / DIM; \
    const float* Xp_ = (st_ == 0) ? xt : ((st_ == 1) ? xa : xv); \
    const float* Xr_ = Xp_ + rowoff + (gc_ - st_ * DIM); \
    A0 = *(const float4*)(Xr_);      A1 = *(const float4*)(Xr_ + 4); \
    A2 = *(const float4*)(Xr_ + 32); A3 = *(const float4*)(Xr_ + 36); }

#define BLOAD(C, B00, B01, B10, B11) { \
    const unsigned short* bp = Bpk + ((khalf * 18 + (C)) << 11) + (l << 3); \
    B00 = *(const bf16x8*)(bp); \
    B01 = *(const bf16x8*)(bp + 512); \
    B10 = *(const bf16x8*)(bp + 1024); \
    B11 = *(const bf16x8*)(bp + 1536); }

#define CMPT(A0, A1, A2, A3, B00, B01, B10, B11) { \
    const bf16x8 fA0 = pack8(A0, A1); \
    const bf16x8 fA1 = pack8(A2, A3); \
    acc0 = __builtin_amdgcn_mfma_f32_16x16x32_bf16(fA0, B00, acc0, 0, 0, 0); \
    acc1 = __builtin_amdgcn_mfma_f32_16x16x32_bf16(fA0, B01, acc1, 0, 0, 0); \
    acc0 = __builtin_amdgcn_mfma_f32_16x16x32_bf16(fA1, B10, acc0, 0, 0, 0); \
    acc1 = __builtin_amdgcn_mfma_f32_16x16x32_bf16(fA1, B11, acc1, 0, 0, 0); }

__global__ __launch_bounds__(256, 6) void k_main(
    const float* __restrict__ xt, const float* __restrict__ xa, const float* __restrict__ xv,
    const unsigned short* __restrict__ Bpk, float* __restrict__ accsum,
    float* __restrict__ qp2)
{
    const int t = threadIdx.x;
    const int l = t & 63;
    const int w = t >> 6;
    const int bid = blockIdx.x;
    const int khalf = bid & 1;
    const int rblk = bid >> 1;
    const int rb0 = rblk << 6;
    const int bb = rblk >> 6;

    const int arow = rb0 + w * 16 + (l & 15);
    const size_t rowoff = (size_t)arow * DIM + (l >> 4) * 8;

    f32x4 acc0 = {0.f, 0.f, 0.f, 0.f};
    f32x4 acc1 = {0.f, 0.f, 0.f, 0.f};

    float4 pa0, pa1, pa2, pa3;
    bf16x8 Ba00, Ba01, Ba10, Ba11;

    #pragma unroll 1
    for (int c = 0; c < 18; ++c) {
        GLOADX(pa0, pa1, pa2, pa3, c)
        BLOAD(c, Ba00, Ba01, Ba10, Ba11)
        CMPT(pa0, pa1, pa2, pa3, Ba00, Ba01, Ba10, Ba11)
    }

    // epilogue: D layout col=lane&15, row=(lane>>4)*4+reg
    const int c_out = l & 15, rgrp = l >> 4;
    float* qph = qp2 + (size_t)khalf * ((size_t)NB * NS * 12);
    if (c_out < 12) {
        const size_t rbase = (size_t)(rb0 + w * 16 + rgrp * 4) * 12 + c_out;
        qph[rbase]      = acc0[0];
        qph[rbase + 12] = acc0[1];
        qph[rbase + 24] = acc0[2];
        qph[rbase + 36] = acc0[3];
    }
    float v = acc1[0] + acc1[1] + acc1[2] + acc1[3];
    v += __shfl_xor(v, 16, 64);
    v += __shfl_xor(v, 32, 64);
    if (rgrp == 0 && c_out < 6)
        atomicAdd(&accsum[bb * NE + c_out], v);
}

// ---------------- kernel D: per-batch global constant ----------------
__global__ __launch_bounds__(256) void k_const(
    const float* __restrict__ xt, const float* __restrict__ xa, const float* __restrict__ xv,
    const float* __restrict__ accsum, const float* __restrict__ A2F,
    const float* __restrict__ cb0, float* __restrict__ constb)
{
    const int b = blockIdx.x, t = threadIdx.x;
    float acc[NE] = {0, 0, 0, 0, 0, 0};
    for (int f = t; f < TD; f += 256) {
        const int st = f / DIM, dd = f - st * DIM;
        const float* Xp = ((st == 0) ? xt : ((st == 1) ? xa : xv)) + (size_t)b * NS * DIM;
        const float dm = Xp[(size_t)(NS - 1) * DIM + dd] - Xp[dd];
        const float* Ap = A2F + f * NE;
        #pragma unroll
        for (int e = 0; e < NE; ++e) acc[e] += dm * Ap[e];
    }
    #pragma unroll
    for (int e = 0; e < NE; ++e)
        for (int m = 1; m < 64; m <<= 1) acc[e] += __shfl_xor(acc[e], m, 64);
    __shared__ float wred[4][NE];
    if ((t & 63) == 0) {
        #pragma unroll
        for (int e = 0; e < NE; ++e) wred[t >> 6][e] = acc[e];
    }
    __syncthreads();
    if (t < NE) {
        const float inv = 1.f / 4096.f;
        const float dsum = wred[0][t] + wred[1][t] + wred[2][t] + wred[3][t];
        constb[b * NE + t] = cb0[t] + accsum[b * NE + t] * inv + dsum * inv;
    }
}

// ---------------- kernel E: combine q - shifted p + const ----------------
__global__ __launch_bounds__(256) void k_add(
    const float* __restrict__ qp2, const float* __restrict__ constb, float* __restrict__ out)
{
    const int row = blockIdx.x * 256 + threadIdx.x;   // 32768 rows exact
    const int b = row >> 12, s = row & (NS - 1);
    const int rowp = (s == 0) ? row : row - 1;
    const size_t H = (size_t)NB * NS * 12;
    const float* q0 = qp2 + (size_t)row * 12;
    const float* q1 = qp2 + H + (size_t)row * 12;
    const float* p0 = qp2 + (size_t)rowp * 12 + 6;
    const float* p1 = qp2 + H + (size_t)rowp * 12 + 6;
    float* op = out + (size_t)row * NE;
    #pragma unroll
    for (int e = 0; e < NE; ++e)
        op[e] = constb[b * NE + e] + q0[e] + q1[e] - p0[e] - p1[e];
}

extern "C" void kernel_launch(void* const* d_in, const int* in_sizes, int n_in,
                              void* d_out, int out_size, void* d_ws, size_t ws_size,
                              hipStream_t stream)
{
    const float* xt     = (const float*)d_in[0];
    const float* xa     = (const float*)d_in[1];
    const float* xv     = (const float*)d_in[2];
    const float* Wspat  = (const float*)d_in[3];
    const float* bspat  = (const float*)d_in[4];
    const float* Wtemp  = (const float*)d_in[5];
    const float* btemp  = (const float*)d_in[6];
    const float* Wsync  = (const float*)d_in[7];
    const float* bsync  = (const float*)d_in[8];
    const float* Wglob  = (const float*)d_in[9];
    const float* bglob  = (const float*)d_in[10];
    const float* Wroute = (const float*)d_in[11];
    const float* broute = (const float*)d_in[12];
    float* out = (float*)d_out;

    float* ws = (float*)d_ws;
    unsigned short* Bpk = (unsigned short*)(ws + OFF_BPK);
    float* A2F    = ws + OFF_A2F;
    float* cb0    = ws + OFF_CB0;
    float* accsum = ws + OFF_ACCSUM;
    float* constb = ws + OFF_CONSTB;
    float* qp2    = ws + OFF_QP2;

    hipMemsetAsync(Bpk, 0, 73728 * sizeof(unsigned short), stream);
    k_fold<<<9, 256, 0, stream>>>(Wspat, Wtemp, Wsync, Wroute, Wglob, bglob,
                                  broute, bspat, btemp, bsync, Bpk, A2F, cb0, accsum);
    k_main<<<1024, 256, 0, stream>>>(xt, xa, xv, Bpk, accsum, qp2);
    k_const<<<8, 256, 0, stream>>>(xt, xa, xv, accsum, A2F, cb0, constb);
    k_add<<<128, 256, 0, stream>>>(qp2, constb, out);
}